// Round 12
// baseline (275.903 us; speedup 1.0000x reference)
//
#include <hip/hip_runtime.h>
#include <cstdint>

#define D_MODEL 1024
#define NH 16
#define DK 64
#define SEQ 2048
#define BATCH 2
#define M_TOT (BATCH * SEQ)   // 4096

typedef __bf16 bf16x8          __attribute__((ext_vector_type(8)));
typedef unsigned short u16x8   __attribute__((ext_vector_type(8)));
typedef float  f32x4           __attribute__((ext_vector_type(4)));

union pun8 { u16x8 u; bf16x8 b; };

__device__ __forceinline__ f32x4 mfma16(bf16x8 a, bf16x8 b, f32x4 c) {
    return __builtin_amdgcn_mfma_f32_16x16x32_bf16(a, b, c, 0, 0, 0);
}

__device__ __forceinline__ unsigned short f2bf(float f) {   // RNE
    union { float f; uint32_t u; } v; v.f = f;
    uint32_t u = v.u;
    return (unsigned short)((u + 0x7FFFu + ((u >> 16) & 1u)) >> 16);
}

__device__ __forceinline__ unsigned short f2bf_trunc(float f) {  // 1-op trunc
    union { float f; uint32_t u; } v; v.f = f;
    return (unsigned short)(v.u >> 16);
}

// async global->LDS, 16 B per lane. LDS dest = wave-uniform base + lane*16.
__device__ __forceinline__ void gl_lds16(const unsigned short* g, unsigned short* l) {
    __builtin_amdgcn_global_load_lds(
        (const __attribute__((address_space(1))) void*)g,
        (__attribute__((address_space(3))) void*)l, 16, 0, 0);
}

// ---------------------------------------------------------------------------
// One-shot fp32 -> bf16 conversion of all 7 inputs (memory-bound pre-pass).
// ---------------------------------------------------------------------------
__global__ __launch_bounds__(256) void convert_all_kernel(
    const float* __restrict__ Q,  const float* __restrict__ K,
    const float* __restrict__ V,  const float* __restrict__ Wq,
    const float* __restrict__ Wk, const float* __restrict__ Wv,
    const float* __restrict__ Wo,
    unsigned short* __restrict__ Qb,  unsigned short* __restrict__ Kb,
    unsigned short* __restrict__ Vb,  unsigned short* __restrict__ Wqb,
    unsigned short* __restrict__ Wkb, unsigned short* __restrict__ Wvb,
    unsigned short* __restrict__ Wob)
{
    int bid = blockIdx.x;
    const float* src; unsigned short* dst; int base;
    if (bid < 3 * 2048) {
        int r = bid >> 11;
        src  = (r == 0) ? Q  : (r == 1) ? K  : V;
        dst  = (r == 0) ? Qb : (r == 1) ? Kb : Vb;
        base = (bid & 2047) * 2048;
    } else {
        int u = bid - 3 * 2048;
        int r = u >> 9;
        src  = (r == 0) ? Wq  : (r == 1) ? Wk  : (r == 2) ? Wv  : Wo;
        dst  = (r == 0) ? Wqb : (r == 1) ? Wkb : (r == 2) ? Wvb : Wob;
        base = (u & 511) * 2048;
    }
    int i = base + threadIdx.x * 8;
    float4 a = *(const float4*)(src + i);
    float4 b = *(const float4*)(src + i + 4);
    u16x8 o;
    o[0] = f2bf(a.x); o[1] = f2bf(a.y); o[2] = f2bf(a.z); o[3] = f2bf(a.w);
    o[4] = f2bf(b.x); o[5] = f2bf(b.y); o[6] = f2bf(b.z); o[7] = f2bf(b.w);
    *(u16x8*)(dst + i) = o;
}

// ---------------------------------------------------------------------------
// Fused QKV projection (unchanged from round 10/11).
// z=0 -> q[B,H,S,Dk], z=1 -> k[B,H,S,Dk], z=2 -> vT[B,H,Dk,S]
// ---------------------------------------------------------------------------
__global__ __launch_bounds__(256) void qkv_proj_kernel(
    const unsigned short* __restrict__ Q,
    const unsigned short* __restrict__ K,
    const unsigned short* __restrict__ V,
    const unsigned short* __restrict__ Wq,
    const unsigned short* __restrict__ Wk,
    const unsigned short* __restrict__ Wv,
    unsigned short* __restrict__ qb,
    unsigned short* __restrict__ kb,
    unsigned short* __restrict__ vtb)
{
    const int z = blockIdx.z;
    const unsigned short* A  = (z == 0) ? Q  : (z == 1) ? K  : V;
    const unsigned short* Bt = (z == 0) ? Wq : (z == 1) ? Wk : Wv;

    const int m0 = blockIdx.y * 128;
    const int n0 = blockIdx.x * 128;

    __shared__ __align__(16) unsigned short smem[128 * 136];
    unsigned short* As = smem;
    unsigned short* Bs = smem + 128 * 32;
    unsigned short* Cs = smem;

    const int t    = threadIdx.x;
    const int lane = t & 63;
    const int w    = t >> 6;
    const int l15  = lane & 15;
    const int quad = lane >> 4;
    const int wm   = (w >> 1) * 64;
    const int wn   = (w & 1) * 64;

    f32x4 acc[4][4] = {};

    for (int k0 = 0; k0 < D_MODEL; k0 += 32) {
        __syncthreads();
        #pragma unroll
        for (int i = 0; i < 2; i++) {
            int u   = t + i * 256;
            int row = u >> 2;
            int kc  = (u & 3) * 8;
            gl_lds16(&A [(m0 + row) * D_MODEL + k0 + kc], &As[(i * 256 + w * 64) * 8]);
            gl_lds16(&Bt[(n0 + row) * D_MODEL + k0 + kc], &Bs[(i * 256 + w * 64) * 8]);
        }
        __syncthreads();

        bf16x8 a[4], b[4];
        #pragma unroll
        for (int mi = 0; mi < 4; mi++)
            a[mi] = *(const bf16x8*)(&As[(wm + mi * 16 + l15) * 32 + quad * 8]);
        #pragma unroll
        for (int ni = 0; ni < 4; ni++)
            b[ni] = *(const bf16x8*)(&Bs[(wn + ni * 16 + l15) * 32 + quad * 8]);

        #pragma unroll
        for (int mi = 0; mi < 4; mi++)
            #pragma unroll
            for (int ni = 0; ni < 4; ni++)
                acc[mi][ni] = mfma16(a[mi], b[ni], acc[mi][ni]);
    }

    // ---- epilogue: repack through LDS, then coalesced 16B stores
    __syncthreads();
    #pragma unroll
    for (int mi = 0; mi < 4; mi++) {
        #pragma unroll
        for (int ni = 0; ni < 4; ni++) {
            #pragma unroll
            for (int r = 0; r < 4; r++) {
                int rloc = wm + mi * 16 + quad * 4 + r;
                int cloc = wn + ni * 16 + l15;
                int rr = (z == 2) ? cloc : rloc;
                int cc = (z == 2) ? rloc : cloc;
                Cs[rr * 136 + cc] = f2bf(acc[mi][ni][r]);
            }
        }
    }
    __syncthreads();
    #pragma unroll
    for (int i = 0; i < 8; i++) {
        int u    = t + i * 256;
        int rrow = u >> 4;
        int cc8  = (u & 15) * 8;
        u16x8 val = *(const u16x8*)(&Cs[rrow * 136 + cc8]);
        unsigned short* dst;
        if (z < 2) {
            int m = m0 + rrow, n = n0 + cc8;
            int bi = m >> 11, s = m & (SEQ - 1);
            int hh = n >> 6,  d = n & (DK - 1);
            dst = ((z == 0) ? qb : kb) + (((size_t)(bi * NH + hh) * SEQ + s) * DK + d);
        } else {
            int dglob = n0 + rrow;
            int bi = m0 >> 11, s = (m0 & (SEQ - 1)) + cc8;
            int hh = dglob >> 6, d = dglob & (DK - 1);
            dst = vtb + (((size_t)(bi * NH + hh) * DK + d) * SEQ + s);
        }
        *(u16x8*)dst = val;
    }
}

// ---------------------------------------------------------------------------
// Flash attention (round 12): 512 threads / 8 waves per block; the staged
// 128-key tile is split ACROSS WAVES (wave w: q-quarter w&3, key-half w>>2)
// instead of processed in two sequential halves. Same grid (512 blocks), same
// global + LDS fragment traffic, same MFMA count — but waves/SIMD 2 -> 4 and
// per-lane exp/VALU work halved. One-time cross-wave (o,l) combine in the
// epilogue (no max-sub => partials add linearly).
// LDS 72.7 KB -> 2 blocks/CU. __launch_bounds__(512,4) pins VGPR <= 128.
// ---------------------------------------------------------------------------
__global__ __launch_bounds__(512, 4) void attn_kernel(
    const unsigned short* __restrict__ qb,
    const unsigned short* __restrict__ kb,
    const unsigned short* __restrict__ vtb,
    unsigned short* __restrict__ ctx)
{
    const int qt = blockIdx.x;  // 0..15 (128 rows each)
    const int h  = blockIdx.y;  // 0..15
    const int b  = blockIdx.z;  // 0..1

    const int t    = threadIdx.x;   // 0..511
    const int lane = t & 63;
    const int w    = t >> 6;        // 0..7
    const int wq   = w & 3;         // q-quarter (32 rows)
    const int wk   = w >> 2;        // key-half (64 keys)
    const int l15  = lane & 15;
    const int quad = lane >> 4;

    const unsigned short* qh = qb  + ((b * NH + h) * SEQ) * DK;
    const unsigned short* kh = kb  + ((b * NH + h) * SEQ) * DK;
    const unsigned short* vh = vtb + ((b * NH + h) * DK) * SEQ;

    // p_lds [8][32][72] = 36,864B | Ks [128][72] = 18,432B | Vs [64][136] = 17,408B
    __shared__ __align__(16) unsigned short smem[8 * 32 * 72 + 128 * 72 + 64 * 136];
    unsigned short* p_lds = smem;                 // per-wave regions
    unsigned short* Ks    = smem + 8 * 32 * 72;
    unsigned short* Vs    = Ks + 128 * 72;

    // Q A-frags: 2 m-frags x 2 k-frags, resident all kernel
    const int qrow0 = qt * 128 + wq * 32;
    bf16x8 qa[2][2];
    #pragma unroll
    for (int m = 0; m < 2; m++)
        #pragma unroll
        for (int kk = 0; kk < 2; kk++)
            qa[m][kk] = *(const bf16x8*)(&qh[(qrow0 + m * 16 + l15) * DK + kk * 32 + quad * 8]);

    pun8 ones_p;
    #pragma unroll
    for (int i = 0; i < 8; i++) ones_p.u[i] = 0x3F80;  // bf16 1.0
    const bf16x8 ones = ones_p.b;

    f32x4 o[2][4] = {};
    f32x4 lacc[2] = {};

    const float c_exp2 = 0.125f * 1.44269504f;   // scale * log2(e)

    for (int kt = 0; kt < SEQ / 128; kt++) {     // 16 iterations
        __syncthreads();   // prior iter's Ks/Vs frag reads complete
        // ---- stage K tile [128 keys][64 d] (1024 chunks over 512 threads)
        #pragma unroll
        for (int i = 0; i < 2; i++) {
            int u   = t + i * 512;       // 0..1023
            int row = u >> 3;            // 0..127
            int c8  = (u & 7) * 8;
            *(u16x8*)(&Ks[row * 72 + c8]) =
                *(const u16x8*)(&kh[(kt * 128 + row) * DK + c8]);
        }
        // ---- stage vT tile [64 d][128 s] (1024 chunks)
        #pragma unroll
        for (int i = 0; i < 2; i++) {
            int u   = t + i * 512;       // 0..1023
            int row = u >> 4;            // 0..63
            int c8  = (u & 15) * 8;      // 0..120
            *(u16x8*)(&Vs[row * 136 + c8]) =
                *(const u16x8*)(&vh[row * SEQ + kt * 128 + c8]);
        }
        __syncthreads();

        // ---- this wave's key-half = wk
        bf16x8 kf[4][2], vf[4][2];
        #pragma unroll
        for (int nb = 0; nb < 4; nb++) {
            const int krow = wk * 64 + nb * 16 + l15;
            kf[nb][0] = *(const bf16x8*)(&Ks[krow * 72 + quad * 8]);
            kf[nb][1] = *(const bf16x8*)(&Ks[krow * 72 + 32 + quad * 8]);
        }
        #pragma unroll
        for (int db = 0; db < 4; db++) {
            vf[db][0] = *(const bf16x8*)(&Vs[(db * 16 + l15) * 136 + wk * 64 + quad * 8]);
            vf[db][1] = *(const bf16x8*)(&Vs[(db * 16 + l15) * 136 + wk * 64 + 32 + quad * 8]);
        }

        // ---- QK^T: C-layout S[q=m*16+quad*4+r][key=nb*16+l15]
        f32x4 sacc[2][4] = {};
        #pragma unroll
        for (int m = 0; m < 2; m++)
            #pragma unroll
            for (int nb = 0; nb < 4; nb++) {
                sacc[m][nb] = mfma16(qa[m][0], kf[nb][0], sacc[m][nb]);
                sacc[m][nb] = mfma16(qa[m][1], kf[nb][1], sacc[m][nb]);
            }

        // ---- p = exp2(s * scale*log2e), truncated bf16 -> wave-private LDS
        #pragma unroll
        for (int m = 0; m < 2; m++)
            #pragma unroll
            for (int nb = 0; nb < 4; nb++)
                #pragma unroll
                for (int r = 0; r < 4; r++) {
                    float p = exp2f(sacc[m][nb][r] * c_exp2);
                    p_lds[(w * 32 + m * 16 + quad * 4 + r) * 72 + nb * 16 + l15] = f2bf_trunc(p);
                }

        asm volatile("" ::: "memory");  // P writes before P reads (wave-private)

        bf16x8 pa[2][2];
        #pragma unroll
        for (int m = 0; m < 2; m++)
            #pragma unroll
            for (int kk = 0; kk < 2; kk++)
                pa[m][kk] = *(const bf16x8*)(&p_lds[(w * 32 + m * 16 + l15) * 72 + kk * 32 + quad * 8]);

        asm volatile("" ::: "memory");  // P reads before next iter's writes

        // ---- PV: o[q][d] += P @ V
        #pragma unroll
        for (int db = 0; db < 4; db++)
            #pragma unroll
            for (int m = 0; m < 2; m++) {
                o[m][db] = mfma16(pa[m][0], vf[db][0], o[m][db]);
                o[m][db] = mfma16(pa[m][1], vf[db][1], o[m][db]);
            }

        // ---- l += P @ ones (same C-layout rows as o)
        #pragma unroll
        for (int m = 0; m < 2; m++) {
            lacc[m] = mfma16(pa[m][0], ones, lacc[m]);
            lacc[m] = mfma16(pa[m][1], ones, lacc[m]);
        }
    }

    // ---- cross-wave combine: wave (wq, wk=1) hands its partial (o,l) to
    // (wq, wk=0) through LDS; then divide and store. Row stride padded to 65
    // to break the 4-quad bank collision.
    __syncthreads();                    // last iter's Ks/Vs reads done
    float* cbuf = (float*)Ks;           // 4 quarters x (32*65 + 32) floats = 33,792 B
    float* myq  = cbuf + wq * (32 * 65 + 32);
    if (wk == 1) {
        #pragma unroll
        for (int m = 0; m < 2; m++) {
            #pragma unroll
            for (int db = 0; db < 4; db++)
                #pragma unroll
                for (int r = 0; r < 4; r++)
                    myq[(m * 16 + quad * 4 + r) * 65 + db * 16 + l15] = o[m][db][r];
            if (l15 == 0)
                #pragma unroll
                for (int r = 0; r < 4; r++)
                    myq[32 * 65 + m * 16 + quad * 4 + r] = lacc[m][r];
        }
    }
    __syncthreads();
    if (wk == 0) {
        #pragma unroll
        for (int m = 0; m < 2; m++) {
            const int row_base = m * 16 + quad * 4;
            float lt[4];
            #pragma unroll
            for (int r = 0; r < 4; r++)
                lt[r] = lacc[m][r] + myq[32 * 65 + row_base + r];  // broadcast read
            const int srow_base = b * SEQ + qt * 128 + wq * 32 + row_base;
            #pragma unroll
            for (int db = 0; db < 4; db++)
                #pragma unroll
                for (int r = 0; r < 4; r++) {
                    float val = (o[m][db][r] + myq[(row_base + r) * 65 + db * 16 + l15]) / lt[r];
                    ctx[(srow_base + r) * D_MODEL + h * DK + db * 16 + l15] = f2bf(val);
                }
        }
    }
}

// ---------------------------------------------------------------------------
// Output projection (unchanged from round 11): 64x128 tiles, 512 blocks.
// ---------------------------------------------------------------------------
__global__ __launch_bounds__(256) void out_proj_kernel(
    const unsigned short* __restrict__ A,
    const unsigned short* __restrict__ Bt,
    float* __restrict__ out)
{
    const int m0 = blockIdx.y * 64;
    const int n0 = blockIdx.x * 128;

    __shared__ __align__(16) unsigned short As[64 * 32];    // 4 KB
    __shared__ __align__(16) unsigned short Bs[128 * 32];   // 8 KB

    const int t    = threadIdx.x;
    const int lane = t & 63;
    const int w    = t >> 6;
    const int l15  = lane & 15;
    const int quad = lane >> 4;
    const int wn   = w * 32;

    f32x4 acc[4][2] = {};

    for (int k0 = 0; k0 < D_MODEL; k0 += 32) {
        __syncthreads();
        {   // As: 256 chunks, 1 per thread
            int row = t >> 2;
            int kc  = (t & 3) * 8;
            gl_lds16(&A[(m0 + row) * D_MODEL + k0 + kc], &As[(w * 64) * 8]);
        }
        #pragma unroll
        for (int i = 0; i < 2; i++) {   // Bs: 512 chunks, 2 per thread
            int u   = t + i * 256;
            int row = u >> 2;
            int kc  = (u & 3) * 8;
            gl_lds16(&Bt[(n0 + row) * D_MODEL + k0 + kc], &Bs[(i * 256 + w * 64) * 8]);
        }
        __syncthreads();

        bf16x8 a[4], bfr[2];
        #pragma unroll
        for (int mi = 0; mi < 4; mi++)
            a[mi] = *(const bf16x8*)(&As[(mi * 16 + l15) * 32 + quad * 8]);
        #pragma unroll
        for (int ni = 0; ni < 2; ni++)
            bfr[ni] = *(const bf16x8*)(&Bs[(wn + ni * 16 + l15) * 32 + quad * 8]);

        #pragma unroll
        for (int mi = 0; mi < 4; mi++)
            #pragma unroll
            for (int ni = 0; ni < 2; ni++)
                acc[mi][ni] = mfma16(a[mi], bfr[ni], acc[mi][ni]);
    }

    #pragma unroll
    for (int mi = 0; mi < 4; mi++) {
        #pragma unroll
        for (int ni = 0; ni < 2; ni++) {
            #pragma unroll
            for (int r = 0; r < 4; r++) {
                int m = m0 + mi * 16 + quad * 4 + r;
                int n = n0 + wn + ni * 16 + l15;
                out[m * D_MODEL + n] = acc[mi][ni][r];
            }
        }
    }
}

extern "C" void kernel_launch(void* const* d_in, const int* in_sizes, int n_in,
                              void* d_out, int out_size, void* d_ws, size_t ws_size,
                              hipStream_t stream) {
    const float* Q  = (const float*)d_in[0];
    const float* K  = (const float*)d_in[1];
    const float* V  = (const float*)d_in[2];
    const float* Wq = (const float*)d_in[3];
    const float* Wk = (const float*)d_in[4];
    const float* Wv = (const float*)d_in[5];
    const float* Wo = (const float*)d_in[6];

    const size_t NQ = (size_t)M_TOT * D_MODEL;     // 4 Mi elements
    const size_t NW = (size_t)D_MODEL * D_MODEL;   // 1 Mi elements

    unsigned short* Qb  = (unsigned short*)d_ws;   // bf16 input copies
    unsigned short* Kb  = Qb  + NQ;
    unsigned short* Vb  = Kb  + NQ;
    unsigned short* Wqb = Vb  + NQ;
    unsigned short* Wkb = Wqb + NW;
    unsigned short* Wvb = Wkb + NW;
    unsigned short* Wob = Wvb + NW;
    unsigned short* qb  = Wob + NW;                // [B,H,S,Dk]
    unsigned short* kbf = qb  + NQ;                // [B,H,S,Dk]
    unsigned short* vtb = kbf + NQ;                // [B,H,Dk,S]
    unsigned short* ctx = vtb + NQ;                // [B*S, D]
    float* out = (float*)d_out;

    convert_all_kernel<<<3 * 2048 + 4 * 512, 256, 0, stream>>>(
        Q, K, V, Wq, Wk, Wv, Wo, Qb, Kb, Vb, Wqb, Wkb, Wvb, Wob);

    dim3 g1(D_MODEL / 128, M_TOT / 128, 3);
    qkv_proj_kernel<<<g1, 256, 0, stream>>>(Qb, Kb, Vb, Wqb, Wkb, Wvb, qb, kbf, vtb);

    dim3 g2(SEQ / 128, NH, BATCH);
    attn_kernel<<<g2, 512, 0, stream>>>(qb, kbf, vtb, ctx);

    dim3 g3(D_MODEL / 128, M_TOT / 64, 1);
    out_proj_kernel<<<g3, 256, 0, stream>>>(ctx, Wob, out);
}

// Round 13
// 261.783 us; speedup vs baseline: 1.0539x; 1.0539x over previous
//
#include <hip/hip_runtime.h>
#include <cstdint>

#define D_MODEL 1024
#define NH 16
#define DK 64
#define SEQ 2048
#define BATCH 2
#define M_TOT (BATCH * SEQ)   // 4096

typedef __bf16 bf16x8          __attribute__((ext_vector_type(8)));
typedef unsigned short u16x8   __attribute__((ext_vector_type(8)));
typedef float  f32x4           __attribute__((ext_vector_type(4)));

union pun8 { u16x8 u; bf16x8 b; };

__device__ __forceinline__ f32x4 mfma16(bf16x8 a, bf16x8 b, f32x4 c) {
    return __builtin_amdgcn_mfma_f32_16x16x32_bf16(a, b, c, 0, 0, 0);
}

__device__ __forceinline__ unsigned short f2bf(float f) {   // RNE
    union { float f; uint32_t u; } v; v.f = f;
    uint32_t u = v.u;
    return (unsigned short)((u + 0x7FFFu + ((u >> 16) & 1u)) >> 16);
}

__device__ __forceinline__ unsigned short f2bf_trunc(float f) {  // 1-op trunc
    union { float f; uint32_t u; } v; v.f = f;
    return (unsigned short)(v.u >> 16);
}

// async global->LDS, 16 B per lane. LDS dest = wave-uniform base + lane*16.
__device__ __forceinline__ void gl_lds16(const unsigned short* g, unsigned short* l) {
    __builtin_amdgcn_global_load_lds(
        (const __attribute__((address_space(1))) void*)g,
        (__attribute__((address_space(3))) void*)l, 16, 0, 0);
}

// ---------------------------------------------------------------------------
// One-shot fp32 -> bf16 conversion of all 7 inputs (memory-bound pre-pass).
// ---------------------------------------------------------------------------
__global__ __launch_bounds__(256) void convert_all_kernel(
    const float* __restrict__ Q,  const float* __restrict__ K,
    const float* __restrict__ V,  const float* __restrict__ Wq,
    const float* __restrict__ Wk, const float* __restrict__ Wv,
    const float* __restrict__ Wo,
    unsigned short* __restrict__ Qb,  unsigned short* __restrict__ Kb,
    unsigned short* __restrict__ Vb,  unsigned short* __restrict__ Wqb,
    unsigned short* __restrict__ Wkb, unsigned short* __restrict__ Wvb,
    unsigned short* __restrict__ Wob)
{
    int bid = blockIdx.x;
    const float* src; unsigned short* dst; int base;
    if (bid < 3 * 2048) {
        int r = bid >> 11;
        src  = (r == 0) ? Q  : (r == 1) ? K  : V;
        dst  = (r == 0) ? Qb : (r == 1) ? Kb : Vb;
        base = (bid & 2047) * 2048;
    } else {
        int u = bid - 3 * 2048;
        int r = u >> 9;
        src  = (r == 0) ? Wq  : (r == 1) ? Wk  : (r == 2) ? Wv  : Wo;
        dst  = (r == 0) ? Wqb : (r == 1) ? Wkb : (r == 2) ? Wvb : Wob;
        base = (u & 511) * 2048;
    }
    int i = base + threadIdx.x * 8;
    float4 a = *(const float4*)(src + i);
    float4 b = *(const float4*)(src + i + 4);
    u16x8 o;
    o[0] = f2bf(a.x); o[1] = f2bf(a.y); o[2] = f2bf(a.z); o[3] = f2bf(a.w);
    o[4] = f2bf(b.x); o[5] = f2bf(b.y); o[6] = f2bf(b.z); o[7] = f2bf(b.w);
    *(u16x8*)(dst + i) = o;
}

// ---------------------------------------------------------------------------
// Fused QKV projection (unchanged from round 10/11).
// z=0 -> q[B,H,S,Dk], z=1 -> k[B,H,S,Dk], z=2 -> vT[B,H,Dk,S]
// ---------------------------------------------------------------------------
__global__ __launch_bounds__(256) void qkv_proj_kernel(
    const unsigned short* __restrict__ Q,
    const unsigned short* __restrict__ K,
    const unsigned short* __restrict__ V,
    const unsigned short* __restrict__ Wq,
    const unsigned short* __restrict__ Wk,
    const unsigned short* __restrict__ Wv,
    unsigned short* __restrict__ qb,
    unsigned short* __restrict__ kb,
    unsigned short* __restrict__ vtb)
{
    const int z = blockIdx.z;
    const unsigned short* A  = (z == 0) ? Q  : (z == 1) ? K  : V;
    const unsigned short* Bt = (z == 0) ? Wq : (z == 1) ? Wk : Wv;

    const int m0 = blockIdx.y * 128;
    const int n0 = blockIdx.x * 128;

    __shared__ __align__(16) unsigned short smem[128 * 136];
    unsigned short* As = smem;
    unsigned short* Bs = smem + 128 * 32;
    unsigned short* Cs = smem;

    const int t    = threadIdx.x;
    const int lane = t & 63;
    const int w    = t >> 6;
    const int l15  = lane & 15;
    const int quad = lane >> 4;
    const int wm   = (w >> 1) * 64;
    const int wn   = (w & 1) * 64;

    f32x4 acc[4][4] = {};

    for (int k0 = 0; k0 < D_MODEL; k0 += 32) {
        __syncthreads();
        #pragma unroll
        for (int i = 0; i < 2; i++) {
            int u   = t + i * 256;
            int row = u >> 2;
            int kc  = (u & 3) * 8;
            gl_lds16(&A [(m0 + row) * D_MODEL + k0 + kc], &As[(i * 256 + w * 64) * 8]);
            gl_lds16(&Bt[(n0 + row) * D_MODEL + k0 + kc], &Bs[(i * 256 + w * 64) * 8]);
        }
        __syncthreads();

        bf16x8 a[4], b[4];
        #pragma unroll
        for (int mi = 0; mi < 4; mi++)
            a[mi] = *(const bf16x8*)(&As[(wm + mi * 16 + l15) * 32 + quad * 8]);
        #pragma unroll
        for (int ni = 0; ni < 4; ni++)
            b[ni] = *(const bf16x8*)(&Bs[(wn + ni * 16 + l15) * 32 + quad * 8]);

        #pragma unroll
        for (int mi = 0; mi < 4; mi++)
            #pragma unroll
            for (int ni = 0; ni < 4; ni++)
                acc[mi][ni] = mfma16(a[mi], b[ni], acc[mi][ni]);
    }

    // ---- epilogue: repack through LDS, then coalesced 16B stores
    __syncthreads();
    #pragma unroll
    for (int mi = 0; mi < 4; mi++) {
        #pragma unroll
        for (int ni = 0; ni < 4; ni++) {
            #pragma unroll
            for (int r = 0; r < 4; r++) {
                int rloc = wm + mi * 16 + quad * 4 + r;
                int cloc = wn + ni * 16 + l15;
                int rr = (z == 2) ? cloc : rloc;
                int cc = (z == 2) ? rloc : cloc;
                Cs[rr * 136 + cc] = f2bf(acc[mi][ni][r]);
            }
        }
    }
    __syncthreads();
    #pragma unroll
    for (int i = 0; i < 8; i++) {
        int u    = t + i * 256;
        int rrow = u >> 4;
        int cc8  = (u & 15) * 8;
        u16x8 val = *(const u16x8*)(&Cs[rrow * 136 + cc8]);
        unsigned short* dst;
        if (z < 2) {
            int m = m0 + rrow, n = n0 + cc8;
            int bi = m >> 11, s = m & (SEQ - 1);
            int hh = n >> 6,  d = n & (DK - 1);
            dst = ((z == 0) ? qb : kb) + (((size_t)(bi * NH + hh) * SEQ + s) * DK + d);
        } else {
            int dglob = n0 + rrow;
            int bi = m0 >> 11, s = (m0 & (SEQ - 1)) + cc8;
            int hh = dglob >> 6, d = dglob & (DK - 1);
            dst = vtb + (((size_t)(bi * NH + hh) * DK + d) * SEQ + s);
        }
        *(u16x8*)dst = val;
    }
}

// ---------------------------------------------------------------------------
// Flash attention (round 13 = round 12 structure, spill fixed):
//  - __launch_bounds__(512, 2): VGPR cap 256, not 64 — R12's forced-64 spilled
//    o/kf/vf to scratch (WRITE_SIZE 8 -> 139 MB, the whole regression).
//  - vf LDS reads DEFERRED to after the P-store section: kf and vf are never
//    live simultaneously -> ~32 VGPRs off the peak, aiming <= 128 for
//    4 waves/SIMD.
//  - 8 waves/block, wave w: q-quarter w&3, key-half w>>2; cross-wave (o,l)
//    combine in epilogue (no max-sub => partials add linearly).
// ---------------------------------------------------------------------------
__global__ __launch_bounds__(512, 2) void attn_kernel(
    const unsigned short* __restrict__ qb,
    const unsigned short* __restrict__ kb,
    const unsigned short* __restrict__ vtb,
    unsigned short* __restrict__ ctx)
{
    const int qt = blockIdx.x;  // 0..15 (128 rows each)
    const int h  = blockIdx.y;  // 0..15
    const int b  = blockIdx.z;  // 0..1

    const int t    = threadIdx.x;   // 0..511
    const int lane = t & 63;
    const int w    = t >> 6;        // 0..7
    const int wq   = w & 3;         // q-quarter (32 rows)
    const int wk   = w >> 2;        // key-half (64 keys)
    const int l15  = lane & 15;
    const int quad = lane >> 4;

    const unsigned short* qh = qb  + ((b * NH + h) * SEQ) * DK;
    const unsigned short* kh = kb  + ((b * NH + h) * SEQ) * DK;
    const unsigned short* vh = vtb + ((b * NH + h) * DK) * SEQ;

    // p_lds [8][32][72] = 36,864B | Ks [128][72] = 18,432B | Vs [64][136] = 17,408B
    __shared__ __align__(16) unsigned short smem[8 * 32 * 72 + 128 * 72 + 64 * 136];
    unsigned short* p_lds = smem;                 // per-wave regions
    unsigned short* Ks    = smem + 8 * 32 * 72;
    unsigned short* Vs    = Ks + 128 * 72;

    // Q A-frags: 2 m-frags x 2 k-frags, resident all kernel
    const int qrow0 = qt * 128 + wq * 32;
    bf16x8 qa[2][2];
    #pragma unroll
    for (int m = 0; m < 2; m++)
        #pragma unroll
        for (int kk = 0; kk < 2; kk++)
            qa[m][kk] = *(const bf16x8*)(&qh[(qrow0 + m * 16 + l15) * DK + kk * 32 + quad * 8]);

    pun8 ones_p;
    #pragma unroll
    for (int i = 0; i < 8; i++) ones_p.u[i] = 0x3F80;  // bf16 1.0
    const bf16x8 ones = ones_p.b;

    f32x4 o[2][4] = {};
    f32x4 lacc[2] = {};

    const float c_exp2 = 0.125f * 1.44269504f;   // scale * log2(e)

    for (int kt = 0; kt < SEQ / 128; kt++) {     // 16 iterations
        __syncthreads();   // prior iter's Ks/Vs frag reads complete
        // ---- stage K tile [128 keys][64 d] (1024 chunks over 512 threads)
        #pragma unroll
        for (int i = 0; i < 2; i++) {
            int u   = t + i * 512;       // 0..1023
            int row = u >> 3;            // 0..127
            int c8  = (u & 7) * 8;
            *(u16x8*)(&Ks[row * 72 + c8]) =
                *(const u16x8*)(&kh[(kt * 128 + row) * DK + c8]);
        }
        // ---- stage vT tile [64 d][128 s] (1024 chunks)
        #pragma unroll
        for (int i = 0; i < 2; i++) {
            int u   = t + i * 512;       // 0..1023
            int row = u >> 4;            // 0..63
            int c8  = (u & 15) * 8;      // 0..120
            *(u16x8*)(&Vs[row * 136 + c8]) =
                *(const u16x8*)(&vh[row * SEQ + kt * 128 + c8]);
        }
        __syncthreads();

        // ---- this wave's key-half = wk: K frags only (vf deferred)
        {
            bf16x8 kf[4][2];
            #pragma unroll
            for (int nb = 0; nb < 4; nb++) {
                const int krow = wk * 64 + nb * 16 + l15;
                kf[nb][0] = *(const bf16x8*)(&Ks[krow * 72 + quad * 8]);
                kf[nb][1] = *(const bf16x8*)(&Ks[krow * 72 + 32 + quad * 8]);
            }

            // ---- QK^T: C-layout S[q=m*16+quad*4+r][key=nb*16+l15]
            f32x4 sacc[2][4] = {};
            #pragma unroll
            for (int m = 0; m < 2; m++)
                #pragma unroll
                for (int nb = 0; nb < 4; nb++) {
                    sacc[m][nb] = mfma16(qa[m][0], kf[nb][0], sacc[m][nb]);
                    sacc[m][nb] = mfma16(qa[m][1], kf[nb][1], sacc[m][nb]);
                }

            // ---- p = exp2(s * scale*log2e), truncated bf16 -> wave-private LDS
            #pragma unroll
            for (int m = 0; m < 2; m++)
                #pragma unroll
                for (int nb = 0; nb < 4; nb++)
                    #pragma unroll
                    for (int r = 0; r < 4; r++) {
                        float p = exp2f(sacc[m][nb][r] * c_exp2);
                        p_lds[(w * 32 + m * 16 + quad * 4 + r) * 72 + nb * 16 + l15] = f2bf_trunc(p);
                    }
        }

        asm volatile("" ::: "memory");  // P writes before P reads (wave-private)

        bf16x8 pa[2][2];
        #pragma unroll
        for (int m = 0; m < 2; m++)
            #pragma unroll
            for (int kk = 0; kk < 2; kk++)
                pa[m][kk] = *(const bf16x8*)(&p_lds[(w * 32 + m * 16 + l15) * 72 + kk * 32 + quad * 8]);

        asm volatile("" ::: "memory");  // P reads before next iter's writes

        // ---- V frags (deferred: kf dead by now -> lower peak VGPR) + PV
        #pragma unroll
        for (int db = 0; db < 4; db++) {
            bf16x8 vf0 = *(const bf16x8*)(&Vs[(db * 16 + l15) * 136 + wk * 64 + quad * 8]);
            bf16x8 vf1 = *(const bf16x8*)(&Vs[(db * 16 + l15) * 136 + wk * 64 + 32 + quad * 8]);
            #pragma unroll
            for (int m = 0; m < 2; m++) {
                o[m][db] = mfma16(pa[m][0], vf0, o[m][db]);
                o[m][db] = mfma16(pa[m][1], vf1, o[m][db]);
            }
        }

        // ---- l += P @ ones (same C-layout rows as o)
        #pragma unroll
        for (int m = 0; m < 2; m++) {
            lacc[m] = mfma16(pa[m][0], ones, lacc[m]);
            lacc[m] = mfma16(pa[m][1], ones, lacc[m]);
        }
    }

    // ---- cross-wave combine: wave (wq, wk=1) hands its partial (o,l) to
    // (wq, wk=0) through LDS; then divide and store. Row stride 65 floats.
    __syncthreads();                    // last iter's Ks/Vs reads done
    float* cbuf = (float*)Ks;           // 4 quarters x (32*65 + 32) floats = 33,792 B
    float* myq  = cbuf + wq * (32 * 65 + 32);
    if (wk == 1) {
        #pragma unroll
        for (int m = 0; m < 2; m++) {
            #pragma unroll
            for (int db = 0; db < 4; db++)
                #pragma unroll
                for (int r = 0; r < 4; r++)
                    myq[(m * 16 + quad * 4 + r) * 65 + db * 16 + l15] = o[m][db][r];
            if (l15 == 0)
                #pragma unroll
                for (int r = 0; r < 4; r++)
                    myq[32 * 65 + m * 16 + quad * 4 + r] = lacc[m][r];
        }
    }
    __syncthreads();
    if (wk == 0) {
        #pragma unroll
        for (int m = 0; m < 2; m++) {
            const int row_base = m * 16 + quad * 4;
            float lt[4];
            #pragma unroll
            for (int r = 0; r < 4; r++)
                lt[r] = lacc[m][r] + myq[32 * 65 + row_base + r];  // broadcast read
            const int srow_base = b * SEQ + qt * 128 + wq * 32 + row_base;
            #pragma unroll
            for (int db = 0; db < 4; db++)
                #pragma unroll
                for (int r = 0; r < 4; r++) {
                    float val = (o[m][db][r] + myq[(row_base + r) * 65 + db * 16 + l15]) / lt[r];
                    ctx[(srow_base + r) * D_MODEL + h * DK + db * 16 + l15] = f2bf(val);
                }
        }
    }
}

// ---------------------------------------------------------------------------
// Output projection (unchanged from round 11): 64x128 tiles, 512 blocks.
// ---------------------------------------------------------------------------
__global__ __launch_bounds__(256) void out_proj_kernel(
    const unsigned short* __restrict__ A,
    const unsigned short* __restrict__ Bt,
    float* __restrict__ out)
{
    const int m0 = blockIdx.y * 64;
    const int n0 = blockIdx.x * 128;

    __shared__ __align__(16) unsigned short As[64 * 32];    // 4 KB
    __shared__ __align__(16) unsigned short Bs[128 * 32];   // 8 KB

    const int t    = threadIdx.x;
    const int lane = t & 63;
    const int w    = t >> 6;
    const int l15  = lane & 15;
    const int quad = lane >> 4;
    const int wn   = w * 32;

    f32x4 acc[4][2] = {};

    for (int k0 = 0; k0 < D_MODEL; k0 += 32) {
        __syncthreads();
        {   // As: 256 chunks, 1 per thread
            int row = t >> 2;
            int kc  = (t & 3) * 8;
            gl_lds16(&A[(m0 + row) * D_MODEL + k0 + kc], &As[(w * 64) * 8]);
        }
        #pragma unroll
        for (int i = 0; i < 2; i++) {   // Bs: 512 chunks, 2 per thread
            int u   = t + i * 256;
            int row = u >> 2;
            int kc  = (u & 3) * 8;
            gl_lds16(&Bt[(n0 + row) * D_MODEL + k0 + kc], &Bs[(i * 256 + w * 64) * 8]);
        }
        __syncthreads();

        bf16x8 a[4], bfr[2];
        #pragma unroll
        for (int mi = 0; mi < 4; mi++)
            a[mi] = *(const bf16x8*)(&As[(mi * 16 + l15) * 32 + quad * 8]);
        #pragma unroll
        for (int ni = 0; ni < 2; ni++)
            bfr[ni] = *(const bf16x8*)(&Bs[(wn + ni * 16 + l15) * 32 + quad * 8]);

        #pragma unroll
        for (int mi = 0; mi < 4; mi++)
            #pragma unroll
            for (int ni = 0; ni < 2; ni++)
                acc[mi][ni] = mfma16(a[mi], bfr[ni], acc[mi][ni]);
    }

    #pragma unroll
    for (int mi = 0; mi < 4; mi++) {
        #pragma unroll
        for (int ni = 0; ni < 2; ni++) {
            #pragma unroll
            for (int r = 0; r < 4; r++) {
                int m = m0 + mi * 16 + quad * 4 + r;
                int n = n0 + wn + ni * 16 + l15;
                out[m * D_MODEL + n] = acc[mi][ni][r];
            }
        }
    }
}

extern "C" void kernel_launch(void* const* d_in, const int* in_sizes, int n_in,
                              void* d_out, int out_size, void* d_ws, size_t ws_size,
                              hipStream_t stream) {
    const float* Q  = (const float*)d_in[0];
    const float* K  = (const float*)d_in[1];
    const float* V  = (const float*)d_in[2];
    const float* Wq = (const float*)d_in[3];
    const float* Wk = (const float*)d_in[4];
    const float* Wv = (const float*)d_in[5];
    const float* Wo = (const float*)d_in[6];

    const size_t NQ = (size_t)M_TOT * D_MODEL;     // 4 Mi elements
    const size_t NW = (size_t)D_MODEL * D_MODEL;   // 1 Mi elements

    unsigned short* Qb  = (unsigned short*)d_ws;   // bf16 input copies
    unsigned short* Kb  = Qb  + NQ;
    unsigned short* Vb  = Kb  + NQ;
    unsigned short* Wqb = Vb  + NQ;
    unsigned short* Wkb = Wqb + NW;
    unsigned short* Wvb = Wkb + NW;
    unsigned short* Wob = Wvb + NW;
    unsigned short* qb  = Wob + NW;                // [B,H,S,Dk]
    unsigned short* kbf = qb  + NQ;                // [B,H,S,Dk]
    unsigned short* vtb = kbf + NQ;                // [B,H,Dk,S]
    unsigned short* ctx = vtb + NQ;                // [B*S, D]
    float* out = (float*)d_out;

    convert_all_kernel<<<3 * 2048 + 4 * 512, 256, 0, stream>>>(
        Q, K, V, Wq, Wk, Wv, Wo, Qb, Kb, Vb, Wqb, Wkb, Wvb, Wob);

    dim3 g1(D_MODEL / 128, M_TOT / 128, 3);
    qkv_proj_kernel<<<g1, 256, 0, stream>>>(Qb, Kb, Vb, Wqb, Wkb, Wvb, qb, kbf, vtb);

    dim3 g2(SEQ / 128, NH, BATCH);
    attn_kernel<<<g2, 512, 0, stream>>>(qb, kbf, vtb, ctx);

    dim3 g3(D_MODEL / 128, M_TOT / 64, 1);
    out_proj_kernel<<<g3, 256, 0, stream>>>(ctx, Wob, out);
}

// Round 14
// 248.070 us; speedup vs baseline: 1.1122x; 1.0553x over previous
//
#include <hip/hip_runtime.h>
#include <cstdint>

#define D_MODEL 1024
#define NH 16
#define DK 64
#define SEQ 2048
#define BATCH 2
#define M_TOT (BATCH * SEQ)   // 4096

typedef __bf16 bf16x8          __attribute__((ext_vector_type(8)));
typedef unsigned short u16x8   __attribute__((ext_vector_type(8)));
typedef float  f32x4           __attribute__((ext_vector_type(4)));

union pun8 { u16x8 u; bf16x8 b; };

__device__ __forceinline__ f32x4 mfma16(bf16x8 a, bf16x8 b, f32x4 c) {
    return __builtin_amdgcn_mfma_f32_16x16x32_bf16(a, b, c, 0, 0, 0);
}

__device__ __forceinline__ unsigned short f2bf(float f) {   // RNE
    union { float f; uint32_t u; } v; v.f = f;
    uint32_t u = v.u;
    return (unsigned short)((u + 0x7FFFu + ((u >> 16) & 1u)) >> 16);
}

__device__ __forceinline__ unsigned short f2bf_trunc(float f) {  // 1-op trunc
    union { float f; uint32_t u; } v; v.f = f;
    return (unsigned short)(v.u >> 16);
}

// async global->LDS, 16 B per lane. LDS dest = wave-uniform base + lane*16.
__device__ __forceinline__ void gl_lds16(const unsigned short* g, unsigned short* l) {
    __builtin_amdgcn_global_load_lds(
        (const __attribute__((address_space(1))) void*)g,
        (__attribute__((address_space(3))) void*)l, 16, 0, 0);
}

// ---------------------------------------------------------------------------
// One-shot fp32 -> bf16 conversion of all 7 inputs (memory-bound pre-pass).
// ---------------------------------------------------------------------------
__global__ __launch_bounds__(256) void convert_all_kernel(
    const float* __restrict__ Q,  const float* __restrict__ K,
    const float* __restrict__ V,  const float* __restrict__ Wq,
    const float* __restrict__ Wk, const float* __restrict__ Wv,
    const float* __restrict__ Wo,
    unsigned short* __restrict__ Qb,  unsigned short* __restrict__ Kb,
    unsigned short* __restrict__ Vb,  unsigned short* __restrict__ Wqb,
    unsigned short* __restrict__ Wkb, unsigned short* __restrict__ Wvb,
    unsigned short* __restrict__ Wob)
{
    int bid = blockIdx.x;
    const float* src; unsigned short* dst; int base;
    if (bid < 3 * 2048) {
        int r = bid >> 11;
        src  = (r == 0) ? Q  : (r == 1) ? K  : V;
        dst  = (r == 0) ? Qb : (r == 1) ? Kb : Vb;
        base = (bid & 2047) * 2048;
    } else {
        int u = bid - 3 * 2048;
        int r = u >> 9;
        src  = (r == 0) ? Wq  : (r == 1) ? Wk  : (r == 2) ? Wv  : Wo;
        dst  = (r == 0) ? Wqb : (r == 1) ? Wkb : (r == 2) ? Wvb : Wob;
        base = (u & 511) * 2048;
    }
    int i = base + threadIdx.x * 8;
    float4 a = *(const float4*)(src + i);
    float4 b = *(const float4*)(src + i + 4);
    u16x8 o;
    o[0] = f2bf(a.x); o[1] = f2bf(a.y); o[2] = f2bf(a.z); o[3] = f2bf(a.w);
    o[4] = f2bf(b.x); o[5] = f2bf(b.y); o[6] = f2bf(b.z); o[7] = f2bf(b.w);
    *(u16x8*)(dst + i) = o;
}

// ---------------------------------------------------------------------------
// Fused QKV projection (round 14): BK=64 — barriers halved (16 pairs, was 32),
// 32 MFMA/wave per staging round (was 16). LDS unchanged (Cs union bound).
// z=0 -> q[B,H,S,Dk], z=1 -> k[B,H,S,Dk], z=2 -> vT[B,H,Dk,S]
// ---------------------------------------------------------------------------
__global__ __launch_bounds__(256) void qkv_proj_kernel(
    const unsigned short* __restrict__ Q,
    const unsigned short* __restrict__ K,
    const unsigned short* __restrict__ V,
    const unsigned short* __restrict__ Wq,
    const unsigned short* __restrict__ Wk,
    const unsigned short* __restrict__ Wv,
    unsigned short* __restrict__ qb,
    unsigned short* __restrict__ kb,
    unsigned short* __restrict__ vtb)
{
    const int z = blockIdx.z;
    const unsigned short* A  = (z == 0) ? Q  : (z == 1) ? K  : V;
    const unsigned short* Bt = (z == 0) ? Wq : (z == 1) ? Wk : Wv;

    const int m0 = blockIdx.y * 128;
    const int n0 = blockIdx.x * 128;

    // As[128][64] 16KB + Bs[128][64] 16KB = 32KB, unioned with Cs[128][136] 34.8KB
    __shared__ __align__(16) unsigned short smem[128 * 136];
    unsigned short* As = smem;
    unsigned short* Bs = smem + 128 * 64;
    unsigned short* Cs = smem;

    const int t    = threadIdx.x;
    const int lane = t & 63;
    const int w    = t >> 6;
    const int l15  = lane & 15;
    const int quad = lane >> 4;
    const int wm   = (w >> 1) * 64;
    const int wn   = (w & 1) * 64;

    f32x4 acc[4][4] = {};

    for (int k0 = 0; k0 < D_MODEL; k0 += 64) {   // 16 iterations
        __syncthreads();
        #pragma unroll
        for (int i = 0; i < 4; i++) {            // 1024 chunks each of As/Bs
            int u   = t + i * 256;
            int row = u >> 3;
            int kc  = (u & 7) * 8;
            gl_lds16(&A [(m0 + row) * D_MODEL + k0 + kc], &As[(i * 256 + w * 64) * 8]);
            gl_lds16(&Bt[(n0 + row) * D_MODEL + k0 + kc], &Bs[(i * 256 + w * 64) * 8]);
        }
        __syncthreads();

        #pragma unroll
        for (int kk = 0; kk < 2; kk++) {
            bf16x8 a[4], b[4];
            #pragma unroll
            for (int mi = 0; mi < 4; mi++)
                a[mi] = *(const bf16x8*)(&As[(wm + mi * 16 + l15) * 64 + kk * 32 + quad * 8]);
            #pragma unroll
            for (int ni = 0; ni < 4; ni++)
                b[ni] = *(const bf16x8*)(&Bs[(wn + ni * 16 + l15) * 64 + kk * 32 + quad * 8]);

            #pragma unroll
            for (int mi = 0; mi < 4; mi++)
                #pragma unroll
                for (int ni = 0; ni < 4; ni++)
                    acc[mi][ni] = mfma16(a[mi], b[ni], acc[mi][ni]);
        }
    }

    // ---- epilogue: repack through LDS, then coalesced 16B stores
    __syncthreads();
    #pragma unroll
    for (int mi = 0; mi < 4; mi++) {
        #pragma unroll
        for (int ni = 0; ni < 4; ni++) {
            #pragma unroll
            for (int r = 0; r < 4; r++) {
                int rloc = wm + mi * 16 + quad * 4 + r;
                int cloc = wn + ni * 16 + l15;
                int rr = (z == 2) ? cloc : rloc;
                int cc = (z == 2) ? rloc : cloc;
                Cs[rr * 136 + cc] = f2bf(acc[mi][ni][r]);
            }
        }
    }
    __syncthreads();
    #pragma unroll
    for (int i = 0; i < 8; i++) {
        int u    = t + i * 256;        // 0..2047 chunks of 16B
        int rrow = u >> 4;             // 0..127
        int cc8  = (u & 15) * 8;       // 0..120
        u16x8 val = *(const u16x8*)(&Cs[rrow * 136 + cc8]);
        unsigned short* dst;
        if (z < 2) {
            int m = m0 + rrow, n = n0 + cc8;
            int bi = m >> 11, s = m & (SEQ - 1);
            int hh = n >> 6,  d = n & (DK - 1);
            dst = ((z == 0) ? qb : kb) + (((size_t)(bi * NH + hh) * SEQ + s) * DK + d);
        } else {
            int dglob = n0 + rrow;
            int bi = m0 >> 11, s = (m0 & (SEQ - 1)) + cc8;
            int hh = dglob >> 6, d = dglob & (DK - 1);
            dst = vtb + (((size_t)(bi * NH + hh) * DK + d) * SEQ + s);
        }
        *(u16x8*)dst = val;
    }
}

// ---------------------------------------------------------------------------
// Flash attention — EXACT round-11 version (measured best: 78.7 us).
// 256 thr / 4 waves, 128-key staged tiles, two barrier-free 64-key halves,
// no max-sub, l via MFMA-with-ones, truncated-bf16 P, wave-private p_lds.
// R12/R13 8-wave variants measured worse (90-103 us) — do not revisit.
// ---------------------------------------------------------------------------
__global__ __launch_bounds__(256) void attn_kernel(
    const unsigned short* __restrict__ qb,
    const unsigned short* __restrict__ kb,
    const unsigned short* __restrict__ vtb,
    unsigned short* __restrict__ ctx)
{
    const int qt = blockIdx.x;  // 0..15 (128 rows each)
    const int h  = blockIdx.y;  // 0..15
    const int b  = blockIdx.z;  // 0..1

    const int t    = threadIdx.x;
    const int lane = t & 63;
    const int w    = t >> 6;
    const int l15  = lane & 15;
    const int quad = lane >> 4;

    const unsigned short* qh = qb  + ((b * NH + h) * SEQ) * DK;
    const unsigned short* kh = kb  + ((b * NH + h) * SEQ) * DK;
    const unsigned short* vh = vtb + ((b * NH + h) * DK) * SEQ;

    __shared__ __align__(16) unsigned short p_lds[4][32][72];  // 18.0 KB
    __shared__ __align__(16) unsigned short Ks[128 * 72];      // 18.0 KB
    __shared__ __align__(16) unsigned short Vs[64 * 136];      // 17.0 KB

    const int qrow0 = qt * 128 + w * 32;
    bf16x8 qa[2][2];
    #pragma unroll
    for (int m = 0; m < 2; m++)
        #pragma unroll
        for (int kk = 0; kk < 2; kk++)
            qa[m][kk] = *(const bf16x8*)(&qh[(qrow0 + m * 16 + l15) * DK + kk * 32 + quad * 8]);

    pun8 ones_p;
    #pragma unroll
    for (int i = 0; i < 8; i++) ones_p.u[i] = 0x3F80;  // bf16 1.0
    const bf16x8 ones = ones_p.b;

    f32x4 o[2][4] = {};
    f32x4 lacc[2] = {};

    const float c_exp2 = 0.125f * 1.44269504f;   // scale * log2(e)

    for (int kt = 0; kt < SEQ / 128; kt++) {     // 16 iterations
        __syncthreads();
        #pragma unroll
        for (int i = 0; i < 4; i++) {
            int u   = t + i * 256;       // 0..1023
            int row = u >> 3;            // 0..127
            int c8  = (u & 7) * 8;
            *(u16x8*)(&Ks[row * 72 + c8]) =
                *(const u16x8*)(&kh[(kt * 128 + row) * DK + c8]);
        }
        #pragma unroll
        for (int i = 0; i < 4; i++) {
            int u   = t + i * 256;       // 0..1023
            int row = u >> 4;            // 0..63
            int c8  = (u & 15) * 8;      // 0..120
            *(u16x8*)(&Vs[row * 136 + c8]) =
                *(const u16x8*)(&vh[row * SEQ + kt * 128 + c8]);
        }
        __syncthreads();

        #pragma unroll
        for (int hh = 0; hh < 2; hh++) {
            bf16x8 kf[4][2], vf[4][2];
            #pragma unroll
            for (int nb = 0; nb < 4; nb++) {
                const int krow = hh * 64 + nb * 16 + l15;
                kf[nb][0] = *(const bf16x8*)(&Ks[krow * 72 + quad * 8]);
                kf[nb][1] = *(const bf16x8*)(&Ks[krow * 72 + 32 + quad * 8]);
            }
            #pragma unroll
            for (int db = 0; db < 4; db++) {
                vf[db][0] = *(const bf16x8*)(&Vs[(db * 16 + l15) * 136 + hh * 64 + quad * 8]);
                vf[db][1] = *(const bf16x8*)(&Vs[(db * 16 + l15) * 136 + hh * 64 + 32 + quad * 8]);
            }

            f32x4 sacc[2][4] = {};
            #pragma unroll
            for (int m = 0; m < 2; m++)
                #pragma unroll
                for (int nb = 0; nb < 4; nb++) {
                    sacc[m][nb] = mfma16(qa[m][0], kf[nb][0], sacc[m][nb]);
                    sacc[m][nb] = mfma16(qa[m][1], kf[nb][1], sacc[m][nb]);
                }

            #pragma unroll
            for (int m = 0; m < 2; m++)
                #pragma unroll
                for (int nb = 0; nb < 4; nb++)
                    #pragma unroll
                    for (int r = 0; r < 4; r++) {
                        float p = exp2f(sacc[m][nb][r] * c_exp2);
                        p_lds[w][m * 16 + quad * 4 + r][nb * 16 + l15] = f2bf_trunc(p);
                    }

            asm volatile("" ::: "memory");  // P writes before P reads (wave-private)

            bf16x8 pa[2][2];
            #pragma unroll
            for (int m = 0; m < 2; m++)
                #pragma unroll
                for (int kk = 0; kk < 2; kk++)
                    pa[m][kk] = *(const bf16x8*)(&p_lds[w][m * 16 + l15][kk * 32 + quad * 8]);

            asm volatile("" ::: "memory");  // P reads before next half's writes

            #pragma unroll
            for (int db = 0; db < 4; db++)
                #pragma unroll
                for (int m = 0; m < 2; m++) {
                    o[m][db] = mfma16(pa[m][0], vf[db][0], o[m][db]);
                    o[m][db] = mfma16(pa[m][1], vf[db][1], o[m][db]);
                }

            #pragma unroll
            for (int m = 0; m < 2; m++) {
                lacc[m] = mfma16(pa[m][0], ones, lacc[m]);
                lacc[m] = mfma16(pa[m][1], ones, lacc[m]);
            }
        }
    }

    #pragma unroll
    for (int m = 0; m < 2; m++) {
        const int srow_base = b * SEQ + qt * 128 + w * 32 + m * 16 + quad * 4;
        #pragma unroll
        for (int db = 0; db < 4; db++)
            #pragma unroll
            for (int r = 0; r < 4; r++) {
                float val = o[m][db][r] / lacc[m][r];
                ctx[(srow_base + r) * D_MODEL + h * DK + db * 16 + l15] = f2bf(val);
            }
    }
}

// ---------------------------------------------------------------------------
// Output projection (round 14): 64x128 tiles + BK=64 (barriers halved).
// ---------------------------------------------------------------------------
__global__ __launch_bounds__(256) void out_proj_kernel(
    const unsigned short* __restrict__ A,
    const unsigned short* __restrict__ Bt,
    float* __restrict__ out)
{
    const int m0 = blockIdx.y * 64;
    const int n0 = blockIdx.x * 128;

    __shared__ __align__(16) unsigned short As[64 * 64];    // 8 KB
    __shared__ __align__(16) unsigned short Bs[128 * 64];   // 16 KB

    const int t    = threadIdx.x;
    const int lane = t & 63;
    const int w    = t >> 6;
    const int l15  = lane & 15;
    const int quad = lane >> 4;
    const int wn   = w * 32;

    f32x4 acc[4][2] = {};

    for (int k0 = 0; k0 < D_MODEL; k0 += 64) {   // 16 iterations
        __syncthreads();
        #pragma unroll
        for (int i = 0; i < 2; i++) {   // As: 512 chunks
            int u   = t + i * 256;
            int row = u >> 3;
            int kc  = (u & 7) * 8;
            gl_lds16(&A[(m0 + row) * D_MODEL + k0 + kc], &As[(i * 256 + w * 64) * 8]);
        }
        #pragma unroll
        for (int i = 0; i < 4; i++) {   // Bs: 1024 chunks
            int u   = t + i * 256;
            int row = u >> 3;
            int kc  = (u & 7) * 8;
            gl_lds16(&Bt[(n0 + row) * D_MODEL + k0 + kc], &Bs[(i * 256 + w * 64) * 8]);
        }
        __syncthreads();

        #pragma unroll
        for (int kk = 0; kk < 2; kk++) {
            bf16x8 a[4], bfr[2];
            #pragma unroll
            for (int mi = 0; mi < 4; mi++)
                a[mi] = *(const bf16x8*)(&As[(mi * 16 + l15) * 64 + kk * 32 + quad * 8]);
            #pragma unroll
            for (int ni = 0; ni < 2; ni++)
                bfr[ni] = *(const bf16x8*)(&Bs[(wn + ni * 16 + l15) * 64 + kk * 32 + quad * 8]);

            #pragma unroll
            for (int mi = 0; mi < 4; mi++)
                #pragma unroll
                for (int ni = 0; ni < 2; ni++)
                    acc[mi][ni] = mfma16(a[mi], bfr[ni], acc[mi][ni]);
        }
    }

    #pragma unroll
    for (int mi = 0; mi < 4; mi++) {
        #pragma unroll
        for (int ni = 0; ni < 2; ni++) {
            #pragma unroll
            for (int r = 0; r < 4; r++) {
                int m = m0 + mi * 16 + quad * 4 + r;
                int n = n0 + wn + ni * 16 + l15;
                out[m * D_MODEL + n] = acc[mi][ni][r];
            }
        }
    }
}

extern "C" void kernel_launch(void* const* d_in, const int* in_sizes, int n_in,
                              void* d_out, int out_size, void* d_ws, size_t ws_size,
                              hipStream_t stream) {
    const float* Q  = (const float*)d_in[0];
    const float* K  = (const float*)d_in[1];
    const float* V  = (const float*)d_in[2];
    const float* Wq = (const float*)d_in[3];
    const float* Wk = (const float*)d_in[4];
    const float* Wv = (const float*)d_in[5];
    const float* Wo = (const float*)d_in[6];

    const size_t NQ = (size_t)M_TOT * D_MODEL;     // 4 Mi elements
    const size_t NW = (size_t)D_MODEL * D_MODEL;   // 1 Mi elements

    unsigned short* Qb  = (unsigned short*)d_ws;   // bf16 input copies
    unsigned short* Kb  = Qb  + NQ;
    unsigned short* Vb  = Kb  + NQ;
    unsigned short* Wqb = Vb  + NQ;
    unsigned short* Wkb = Wqb + NW;
    unsigned short* Wvb = Wkb + NW;
    unsigned short* Wob = Wvb + NW;
    unsigned short* qb  = Wob + NW;                // [B,H,S,Dk]
    unsigned short* kbf = qb  + NQ;                // [B,H,S,Dk]
    unsigned short* vtb = kbf + NQ;                // [B,H,Dk,S]
    unsigned short* ctx = vtb + NQ;                // [B*S, D]
    float* out = (float*)d_out;

    convert_all_kernel<<<3 * 2048 + 4 * 512, 256, 0, stream>>>(
        Q, K, V, Wq, Wk, Wv, Wo, Qb, Kb, Vb, Wqb, Wkb, Wvb, Wob);

    dim3 g1(D_MODEL / 128, M_TOT / 128, 3);
    qkv_proj_kernel<<<g1, 256, 0, stream>>>(Qb, Kb, Vb, Wqb, Wkb, Wvb, qb, kbf, vtb);

    dim3 g2(SEQ / 128, NH, BATCH);
    attn_kernel<<<g2, 256, 0, stream>>>(qb, kbf, vtb, ctx);

    dim3 g3(D_MODEL / 128, M_TOT / 64, 1);
    out_proj_kernel<<<g3, 256, 0, stream>>>(ctx, Wob, out);
}

// Round 15
// 232.836 us; speedup vs baseline: 1.1850x; 1.0654x over previous
//
#include <hip/hip_runtime.h>
#include <cstdint>

#define D_MODEL 1024
#define NH 16
#define DK 64
#define SEQ 2048
#define BATCH 2
#define M_TOT (BATCH * SEQ)   // 4096

typedef __bf16 bf16x8          __attribute__((ext_vector_type(8)));
typedef unsigned short u16x8   __attribute__((ext_vector_type(8)));
typedef float  f32x4           __attribute__((ext_vector_type(4)));

union pun8 { u16x8 u; bf16x8 b; };

__device__ __forceinline__ f32x4 mfma16(bf16x8 a, bf16x8 b, f32x4 c) {
    return __builtin_amdgcn_mfma_f32_16x16x32_bf16(a, b, c, 0, 0, 0);
}

__device__ __forceinline__ unsigned short f2bf(float f) {   // RNE
    union { float f; uint32_t u; } v; v.f = f;
    uint32_t u = v.u;
    return (unsigned short)((u + 0x7FFFu + ((u >> 16) & 1u)) >> 16);
}

__device__ __forceinline__ unsigned short f2bf_trunc(float f) {  // 1-op trunc
    union { float f; uint32_t u; } v; v.f = f;
    return (unsigned short)(v.u >> 16);
}

// async global->LDS, 16 B per lane. LDS dest = wave-uniform base + lane*16.
__device__ __forceinline__ void gl_lds16(const unsigned short* g, unsigned short* l) {
    __builtin_amdgcn_global_load_lds(
        (const __attribute__((address_space(1))) void*)g,
        (__attribute__((address_space(3))) void*)l, 16, 0, 0);
}

// softmax scale folded into exp2 argument; baked into q at projection time
#define C_EXP2 0.1803368801111204f   // 0.125 * log2(e)

// ---------------------------------------------------------------------------
// One-shot fp32 -> bf16 conversion of all 7 inputs (memory-bound pre-pass).
// ---------------------------------------------------------------------------
__global__ __launch_bounds__(256) void convert_all_kernel(
    const float* __restrict__ Q,  const float* __restrict__ K,
    const float* __restrict__ V,  const float* __restrict__ Wq,
    const float* __restrict__ Wk, const float* __restrict__ Wv,
    const float* __restrict__ Wo,
    unsigned short* __restrict__ Qb,  unsigned short* __restrict__ Kb,
    unsigned short* __restrict__ Vb,  unsigned short* __restrict__ Wqb,
    unsigned short* __restrict__ Wkb, unsigned short* __restrict__ Wvb,
    unsigned short* __restrict__ Wob)
{
    int bid = blockIdx.x;
    const float* src; unsigned short* dst; int base;
    if (bid < 3 * 2048) {
        int r = bid >> 11;
        src  = (r == 0) ? Q  : (r == 1) ? K  : V;
        dst  = (r == 0) ? Qb : (r == 1) ? Kb : Vb;
        base = (bid & 2047) * 2048;
    } else {
        int u = bid - 3 * 2048;
        int r = u >> 9;
        src  = (r == 0) ? Wq  : (r == 1) ? Wk  : (r == 2) ? Wv  : Wo;
        dst  = (r == 0) ? Wqb : (r == 1) ? Wkb : (r == 2) ? Wvb : Wob;
        base = (u & 511) * 2048;
    }
    int i = base + threadIdx.x * 8;
    float4 a = *(const float4*)(src + i);
    float4 b = *(const float4*)(src + i + 4);
    u16x8 o;
    o[0] = f2bf(a.x); o[1] = f2bf(a.y); o[2] = f2bf(a.z); o[3] = f2bf(a.w);
    o[4] = f2bf(b.x); o[5] = f2bf(b.y); o[6] = f2bf(b.z); o[7] = f2bf(b.w);
    *(u16x8*)(dst + i) = o;
}

// ---------------------------------------------------------------------------
// Fused QKV projection (round 15): q values PRE-SCALED by 0.125*log2e in the
// epilogue (z==0) so attn's per-score multiply disappears. BK=64 otherwise
// unchanged from R14.
// z=0 -> q_scaled[B,H,S,Dk], z=1 -> k[B,H,S,Dk], z=2 -> vT[B,H,Dk,S]
// ---------------------------------------------------------------------------
__global__ __launch_bounds__(256) void qkv_proj_kernel(
    const unsigned short* __restrict__ Q,
    const unsigned short* __restrict__ K,
    const unsigned short* __restrict__ V,
    const unsigned short* __restrict__ Wq,
    const unsigned short* __restrict__ Wk,
    const unsigned short* __restrict__ Wv,
    unsigned short* __restrict__ qb,
    unsigned short* __restrict__ kb,
    unsigned short* __restrict__ vtb)
{
    const int z = blockIdx.z;
    const unsigned short* A  = (z == 0) ? Q  : (z == 1) ? K  : V;
    const unsigned short* Bt = (z == 0) ? Wq : (z == 1) ? Wk : Wv;

    const int m0 = blockIdx.y * 128;
    const int n0 = blockIdx.x * 128;

    __shared__ __align__(16) unsigned short smem[128 * 136];
    unsigned short* As = smem;
    unsigned short* Bs = smem + 128 * 64;
    unsigned short* Cs = smem;

    const int t    = threadIdx.x;
    const int lane = t & 63;
    const int w    = t >> 6;
    const int l15  = lane & 15;
    const int quad = lane >> 4;
    const int wm   = (w >> 1) * 64;
    const int wn   = (w & 1) * 64;

    f32x4 acc[4][4] = {};

    for (int k0 = 0; k0 < D_MODEL; k0 += 64) {   // 16 iterations
        __syncthreads();
        #pragma unroll
        for (int i = 0; i < 4; i++) {
            int u   = t + i * 256;
            int row = u >> 3;
            int kc  = (u & 7) * 8;
            gl_lds16(&A [(m0 + row) * D_MODEL + k0 + kc], &As[(i * 256 + w * 64) * 8]);
            gl_lds16(&Bt[(n0 + row) * D_MODEL + k0 + kc], &Bs[(i * 256 + w * 64) * 8]);
        }
        __syncthreads();

        #pragma unroll
        for (int kk = 0; kk < 2; kk++) {
            bf16x8 a[4], b[4];
            #pragma unroll
            for (int mi = 0; mi < 4; mi++)
                a[mi] = *(const bf16x8*)(&As[(wm + mi * 16 + l15) * 64 + kk * 32 + quad * 8]);
            #pragma unroll
            for (int ni = 0; ni < 4; ni++)
                b[ni] = *(const bf16x8*)(&Bs[(wn + ni * 16 + l15) * 64 + kk * 32 + quad * 8]);

            #pragma unroll
            for (int mi = 0; mi < 4; mi++)
                #pragma unroll
                for (int ni = 0; ni < 4; ni++)
                    acc[mi][ni] = mfma16(a[mi], b[ni], acc[mi][ni]);
        }
    }

    // ---- epilogue: repack through LDS, then coalesced 16B stores
    const float oscale = (z == 0) ? C_EXP2 : 1.0f;   // fold softmax scale into q
    __syncthreads();
    #pragma unroll
    for (int mi = 0; mi < 4; mi++) {
        #pragma unroll
        for (int ni = 0; ni < 4; ni++) {
            #pragma unroll
            for (int r = 0; r < 4; r++) {
                int rloc = wm + mi * 16 + quad * 4 + r;
                int cloc = wn + ni * 16 + l15;
                int rr = (z == 2) ? cloc : rloc;
                int cc = (z == 2) ? rloc : cloc;
                Cs[rr * 136 + cc] = f2bf(acc[mi][ni][r] * oscale);
            }
        }
    }
    __syncthreads();
    #pragma unroll
    for (int i = 0; i < 8; i++) {
        int u    = t + i * 256;
        int rrow = u >> 4;
        int cc8  = (u & 15) * 8;
        u16x8 val = *(const u16x8*)(&Cs[rrow * 136 + cc8]);
        unsigned short* dst;
        if (z < 2) {
            int m = m0 + rrow, n = n0 + cc8;
            int bi = m >> 11, s = m & (SEQ - 1);
            int hh = n >> 6,  d = n & (DK - 1);
            dst = ((z == 0) ? qb : kb) + (((size_t)(bi * NH + hh) * SEQ + s) * DK + d);
        } else {
            int dglob = n0 + rrow;
            int bi = m0 >> 11, s = (m0 & (SEQ - 1)) + cc8;
            int hh = dglob >> 6, d = dglob & (DK - 1);
            dst = vtb + (((size_t)(bi * NH + hh) * DK + d) * SEQ + s);
        }
        *(u16x8*)dst = val;
    }
}

// ---------------------------------------------------------------------------
// Flash attention (round 15 = R11/R14 best shape + two micro-opts):
//  - grid swizzled h-FASTEST (blockIdx.x=h): the 16 qt-blocks sharing one
//    head's K/V no longer run simultaneously on all 8 XCDs -> fewer L2-miss
//    refetches (FETCH 69.7 MB -> pred ~40 MB)
//  - q pre-scaled at projection: p = exp2(sacc) directly (no per-score mul)
// ---------------------------------------------------------------------------
__global__ __launch_bounds__(256) void attn_kernel(
    const unsigned short* __restrict__ qb,
    const unsigned short* __restrict__ kb,
    const unsigned short* __restrict__ vtb,
    unsigned short* __restrict__ ctx)
{
    const int h  = blockIdx.x;  // 0..15  (h fastest -> XCD spread across heads)
    const int qt = blockIdx.y;  // 0..15 (128 rows each)
    const int b  = blockIdx.z;  // 0..1

    const int t    = threadIdx.x;
    const int lane = t & 63;
    const int w    = t >> 6;
    const int l15  = lane & 15;
    const int quad = lane >> 4;

    const unsigned short* qh = qb  + ((b * NH + h) * SEQ) * DK;
    const unsigned short* kh = kb  + ((b * NH + h) * SEQ) * DK;
    const unsigned short* vh = vtb + ((b * NH + h) * DK) * SEQ;

    __shared__ __align__(16) unsigned short p_lds[4][32][72];  // 18.0 KB
    __shared__ __align__(16) unsigned short Ks[128 * 72];      // 18.0 KB
    __shared__ __align__(16) unsigned short Vs[64 * 136];      // 17.0 KB

    const int qrow0 = qt * 128 + w * 32;
    bf16x8 qa[2][2];
    #pragma unroll
    for (int m = 0; m < 2; m++)
        #pragma unroll
        for (int kk = 0; kk < 2; kk++)
            qa[m][kk] = *(const bf16x8*)(&qh[(qrow0 + m * 16 + l15) * DK + kk * 32 + quad * 8]);

    pun8 ones_p;
    #pragma unroll
    for (int i = 0; i < 8; i++) ones_p.u[i] = 0x3F80;  // bf16 1.0
    const bf16x8 ones = ones_p.b;

    f32x4 o[2][4] = {};
    f32x4 lacc[2] = {};

    for (int kt = 0; kt < SEQ / 128; kt++) {     // 16 iterations
        __syncthreads();
        #pragma unroll
        for (int i = 0; i < 4; i++) {
            int u   = t + i * 256;       // 0..1023
            int row = u >> 3;            // 0..127
            int c8  = (u & 7) * 8;
            *(u16x8*)(&Ks[row * 72 + c8]) =
                *(const u16x8*)(&kh[(kt * 128 + row) * DK + c8]);
        }
        #pragma unroll
        for (int i = 0; i < 4; i++) {
            int u   = t + i * 256;       // 0..1023
            int row = u >> 4;            // 0..63
            int c8  = (u & 15) * 8;      // 0..120
            *(u16x8*)(&Vs[row * 136 + c8]) =
                *(const u16x8*)(&vh[row * SEQ + kt * 128 + c8]);
        }
        __syncthreads();

        #pragma unroll
        for (int hh = 0; hh < 2; hh++) {
            bf16x8 kf[4][2], vf[4][2];
            #pragma unroll
            for (int nb = 0; nb < 4; nb++) {
                const int krow = hh * 64 + nb * 16 + l15;
                kf[nb][0] = *(const bf16x8*)(&Ks[krow * 72 + quad * 8]);
                kf[nb][1] = *(const bf16x8*)(&Ks[krow * 72 + 32 + quad * 8]);
            }
            #pragma unroll
            for (int db = 0; db < 4; db++) {
                vf[db][0] = *(const bf16x8*)(&Vs[(db * 16 + l15) * 136 + hh * 64 + quad * 8]);
                vf[db][1] = *(const bf16x8*)(&Vs[(db * 16 + l15) * 136 + hh * 64 + 32 + quad * 8]);
            }

            f32x4 sacc[2][4] = {};
            #pragma unroll
            for (int m = 0; m < 2; m++)
                #pragma unroll
                for (int nb = 0; nb < 4; nb++) {
                    sacc[m][nb] = mfma16(qa[m][0], kf[nb][0], sacc[m][nb]);
                    sacc[m][nb] = mfma16(qa[m][1], kf[nb][1], sacc[m][nb]);
                }

            // p = exp2(sacc)  — scale already baked into q at projection
            #pragma unroll
            for (int m = 0; m < 2; m++)
                #pragma unroll
                for (int nb = 0; nb < 4; nb++)
                    #pragma unroll
                    for (int r = 0; r < 4; r++) {
                        float p = exp2f(sacc[m][nb][r]);
                        p_lds[w][m * 16 + quad * 4 + r][nb * 16 + l15] = f2bf_trunc(p);
                    }

            asm volatile("" ::: "memory");  // P writes before P reads (wave-private)

            bf16x8 pa[2][2];
            #pragma unroll
            for (int m = 0; m < 2; m++)
                #pragma unroll
                for (int kk = 0; kk < 2; kk++)
                    pa[m][kk] = *(const bf16x8*)(&p_lds[w][m * 16 + l15][kk * 32 + quad * 8]);

            asm volatile("" ::: "memory");  // P reads before next half's writes

            #pragma unroll
            for (int db = 0; db < 4; db++)
                #pragma unroll
                for (int m = 0; m < 2; m++) {
                    o[m][db] = mfma16(pa[m][0], vf[db][0], o[m][db]);
                    o[m][db] = mfma16(pa[m][1], vf[db][1], o[m][db]);
                }

            #pragma unroll
            for (int m = 0; m < 2; m++) {
                lacc[m] = mfma16(pa[m][0], ones, lacc[m]);
                lacc[m] = mfma16(pa[m][1], ones, lacc[m]);
            }
        }
    }

    #pragma unroll
    for (int m = 0; m < 2; m++) {
        const int srow_base = b * SEQ + qt * 128 + w * 32 + m * 16 + quad * 4;
        #pragma unroll
        for (int db = 0; db < 4; db++)
            #pragma unroll
            for (int r = 0; r < 4; r++) {
                float val = o[m][db][r] / lacc[m][r];
                ctx[(srow_base + r) * D_MODEL + h * DK + db * 16 + l15] = f2bf(val);
            }
    }
}

// ---------------------------------------------------------------------------
// Output projection (unchanged from round 14): 64x128 tiles, BK=64.
// ---------------------------------------------------------------------------
__global__ __launch_bounds__(256) void out_proj_kernel(
    const unsigned short* __restrict__ A,
    const unsigned short* __restrict__ Bt,
    float* __restrict__ out)
{
    const int m0 = blockIdx.y * 64;
    const int n0 = blockIdx.x * 128;

    __shared__ __align__(16) unsigned short As[64 * 64];    // 8 KB
    __shared__ __align__(16) unsigned short Bs[128 * 64];   // 16 KB

    const int t    = threadIdx.x;
    const int lane = t & 63;
    const int w    = t >> 6;
    const int l15  = lane & 15;
    const int quad = lane >> 4;
    const int wn   = w * 32;

    f32x4 acc[4][2] = {};

    for (int k0 = 0; k0 < D_MODEL; k0 += 64) {   // 16 iterations
        __syncthreads();
        #pragma unroll
        for (int i = 0; i < 2; i++) {
            int u   = t + i * 256;
            int row = u >> 3;
            int kc  = (u & 7) * 8;
            gl_lds16(&A[(m0 + row) * D_MODEL + k0 + kc], &As[(i * 256 + w * 64) * 8]);
        }
        #pragma unroll
        for (int i = 0; i < 4; i++) {
            int u   = t + i * 256;
            int row = u >> 3;
            int kc  = (u & 7) * 8;
            gl_lds16(&Bt[(n0 + row) * D_MODEL + k0 + kc], &Bs[(i * 256 + w * 64) * 8]);
        }
        __syncthreads();

        #pragma unroll
        for (int kk = 0; kk < 2; kk++) {
            bf16x8 a[4], bfr[2];
            #pragma unroll
            for (int mi = 0; mi < 4; mi++)
                a[mi] = *(const bf16x8*)(&As[(mi * 16 + l15) * 64 + kk * 32 + quad * 8]);
            #pragma unroll
            for (int ni = 0; ni < 2; ni++)
                bfr[ni] = *(const bf16x8*)(&Bs[(wn + ni * 16 + l15) * 64 + kk * 32 + quad * 8]);

            #pragma unroll
            for (int mi = 0; mi < 4; mi++)
                #pragma unroll
                for (int ni = 0; ni < 2; ni++)
                    acc[mi][ni] = mfma16(a[mi], bfr[ni], acc[mi][ni]);
        }
    }

    #pragma unroll
    for (int mi = 0; mi < 4; mi++) {
        #pragma unroll
        for (int ni = 0; ni < 2; ni++) {
            #pragma unroll
            for (int r = 0; r < 4; r++) {
                int m = m0 + mi * 16 + quad * 4 + r;
                int n = n0 + wn + ni * 16 + l15;
                out[m * D_MODEL + n] = acc[mi][ni][r];
            }
        }
    }
}

extern "C" void kernel_launch(void* const* d_in, const int* in_sizes, int n_in,
                              void* d_out, int out_size, void* d_ws, size_t ws_size,
                              hipStream_t stream) {
    const float* Q  = (const float*)d_in[0];
    const float* K  = (const float*)d_in[1];
    const float* V  = (const float*)d_in[2];
    const float* Wq = (const float*)d_in[3];
    const float* Wk = (const float*)d_in[4];
    const float* Wv = (const float*)d_in[5];
    const float* Wo = (const float*)d_in[6];

    const size_t NQ = (size_t)M_TOT * D_MODEL;     // 4 Mi elements
    const size_t NW = (size_t)D_MODEL * D_MODEL;   // 1 Mi elements

    unsigned short* Qb  = (unsigned short*)d_ws;   // bf16 input copies
    unsigned short* Kb  = Qb  + NQ;
    unsigned short* Vb  = Kb  + NQ;
    unsigned short* Wqb = Vb  + NQ;
    unsigned short* Wkb = Wqb + NW;
    unsigned short* Wvb = Wkb + NW;
    unsigned short* Wob = Wvb + NW;
    unsigned short* qb  = Wob + NW;                // [B,H,S,Dk] (pre-scaled)
    unsigned short* kbf = qb  + NQ;                // [B,H,S,Dk]
    unsigned short* vtb = kbf + NQ;                // [B,H,Dk,S]
    unsigned short* ctx = vtb + NQ;                // [B*S, D]
    float* out = (float*)d_out;

    convert_all_kernel<<<3 * 2048 + 4 * 512, 256, 0, stream>>>(
        Q, K, V, Wq, Wk, Wv, Wo, Qb, Kb, Vb, Wqb, Wkb, Wvb, Wob);

    dim3 g1(D_MODEL / 128, M_TOT / 128, 3);
    qkv_proj_kernel<<<g1, 256, 0, stream>>>(Qb, Kb, Vb, Wqb, Wkb, Wvb, qb, kbf, vtb);

    dim3 g2(NH, SEQ / 128, BATCH);   // h fastest (XCD swizzle)
    attn_kernel<<<g2, 256, 0, stream>>>(qb, kbf, vtb, ctx);

    dim3 g3(D_MODEL / 128, M_TOT / 64, 1);
    out_proj_kernel<<<g3, 256, 0, stream>>>(ctx, Wob, out);
}